// Round 10
// baseline (100.207 us; speedup 1.0000x reference)
//
#include <hip/hip_runtime.h>

// Fast discrete Radon transform (exact, wrap-around shears), radix-16:
//   case A (m<512):   R_m[t]  = sum_y img[(t - m*y) & 511, y]
//   case B (m>=512):  R'_a[t] = sum_x img[x, (t - 2a*x) & 511], a = m-512
// out = R * (1/sqrt(512)), imag exactly 0.
//
// Stages: 1 ->(init, radix-2, case A only) 2 ->(radix-16) 32 ->(radix-16, fused output) 512.
// Dependency-packed 3-kernel pipeline:
//   K1 = init (case-A transpose+radix-2) || pass1-caseB   (img read 1x HBM, 2nd L3)
//   K2 = pass1-caseA (A0->A1)           || pass2-caseB (B1->out)   [both only need K1]
//   K3 = pass2-caseA (A1->out)
// LDS-gather redundancy elimination (bit-exact); nontemporal output stores.

#define NN 512
#define MU 768
#define MASK 511
#define SCALE 0.04419417382415922f  // 1/sqrt(512)

typedef float f32x2 __attribute__((ext_vector_type(2)));

// ---- shared device bodies ------------------------------------------------

// pass2 gather+store from a 16x512 LDS tile; m(j) = mbase + mstep*j.
__device__ __forceinline__ void pass2_core(const float* L, int t, int c,
                                           int mbase, int mstep, int b,
                                           float2* __restrict__ out) {
  float acc[16];
#pragma unroll
  for (int j = 0; j < 16; ++j) acc[j] = 0.f;
#pragma unroll
  for (int bb = 0; bb < 16; ++bb) {
    const int p = (bb == 0) ? 1
                : ((bb & 1) ? 16 : ((bb & 2) ? 8 : ((bb & 4) ? 4 : 2)));
    const int step = (32 * bb) & MASK;
    const float* row = L + bb * 512;
    int base = (t - c * bb) & MASK;
    float v[16];
#pragma unroll
    for (int k = 0; k < 16; ++k)
      if (k < p) {
        v[k] = row[base];            // consecutive lanes -> consecutive banks
        base = (base - step) & MASK;
      }
#pragma unroll
    for (int j = 0; j < 16; ++j) acc[j] += v[j & (p - 1)];
  }
#pragma unroll
  for (int j = 0; j < 16; ++j) {
    const int m = mbase + mstep * j;
    f32x2 o; o.x = acc[j] * SCALE; o.y = 0.f;
    __builtin_nontemporal_store(o, (f32x2*)&out[((size_t)b * MU + m) * NN + t]);
  }
}

// pass1 radix-16 gather (float4 lanes) from 16x512 LDS; C(jj) = C0 + 8*jj.
__device__ __forceinline__ void pass1_core(const float* L, int t, int C0,
                                           float4* acc) {
#pragma unroll
  for (int jj = 0; jj < 4; ++jj) acc[jj] = make_float4(0.f, 0.f, 0.f, 0.f);
  const int x4 = (t & 127) * 4;
#pragma unroll
  for (int bb = 0; bb < 16; ++bb) {
    const int p = ((bb & 3) == 0) ? 1 : (((bb & 1) == 0) ? 2 : 4);
    const int step = (128 * bb) & MASK;
    int base = (x4 - C0 * bb * 16) & MASK;  // %4==0: no wrap split
    float4 v[4];
#pragma unroll
    for (int k = 0; k < 4; ++k)
      if (k < p) {
        v[k] = *(const float4*)&L[bb * 512 + base];
        base = (base - step) & MASK;
      }
#pragma unroll
    for (int jj = 0; jj < 4; ++jj) {
      const float4 u = v[jj & (p - 1)];
      acc[jj].x += u.x; acc[jj].y += u.y; acc[jj].z += u.z; acc[jj].w += u.w;
    }
  }
}

// ---- K1: blocks 0..31 = init (transpose + radix-2, one barrier);
//          blocks 32..47 = pass1 case-B (img radix-2 fused staging) ---------
__global__ __launch_bounds__(512) void k_init_p1b(const float* __restrict__ img,
                                                  float* __restrict__ A0,
                                                  float* __restrict__ B1) {
  __shared__ float S[4 * 64 * 33];  // 33.8 KB (init); p1B uses 32 KB as L
  const int bx = blockIdx.x, b = blockIdx.y;
  const int t = threadIdx.x;
  const float* src = img + (size_t)b * NN * NN;

  if (bx < 32) {
    // tiles T0=(x0,w0) T1=(x0,w0+256) T2=(x1,w0) T3=(x1,w0+256)
    // outputs: cls0@x0=T0+T1, cls1@x0=T0+T3, cls0@x1=T2+T3, cls1@x1=T2+T1.
    float (*T)[64][33] = (float (*)[64][33])S;
    const int xp = bx >> 3, wt = bx & 7;     // xp<4, wt<8
    const int x0 = xp * 64, x1 = x0 + 256, w0 = wt * 32;
    float* dst = A0 + (size_t)b * (512 * NN);

    for (int idx = t; idx < 2048; idx += 512) {
      const int tile = idx >> 9;             // 0..3
      const int r = (idx >> 3) & 63, c4 = (idx & 7) << 2;
      const int xb = (tile & 2) ? x1 : x0;
      const int wb = (tile & 1) ? (w0 + 256) : w0;
      const float4 v = *(const float4*)&src[(size_t)(xb + r) * NN + wb + c4];
      T[tile][r][c4]     = v.x;
      T[tile][r][c4 + 1] = v.y;
      T[tile][r][c4 + 2] = v.z;
      T[tile][r][c4 + 3] = v.w;
    }
    __syncthreads();
    for (int idx = t; idx < 2048; idx += 512) {
      const int s = idx >> 9;                // 0..3 output set
      const int wl = (idx >> 4) & 31, x4 = (idx & 15) << 2;
      const int ta = (s & 2) ? 2 : 0;
      const int tb = (s == 0) ? 1 : (s == 1) ? 3 : (s == 2) ? 3 : 1;
      const int rbase = ((s & 1) ? 256 : 0) + w0;
      const int cbase = (s & 2) ? x1 : x0;
      float4 a;
      a.x = T[ta][x4][wl]     + T[tb][x4][wl];
      a.y = T[ta][x4 + 1][wl] + T[tb][x4 + 1][wl];
      a.z = T[ta][x4 + 2][wl] + T[tb][x4 + 2][wl];
      a.w = T[ta][x4 + 3][wl] + T[tb][x4 + 3][wl];
      *(float4*)&dst[(size_t)(rbase + wl) * NN + cbase + x4] = a;
    }
  } else {
    // pass1 case-B: w = bx-32; radix-2 over x fused into staging.
    float* L = S;                            // 16*512 floats
    const int w = bx - 32;
    {
      const float4* s4 = (const float4*)src;
      float4* l4 = (float4*)L;
      for (int it = 0; it < 4; ++it) {
        int flat = it * 512 + t;  // 2048 float4
        int lrow = flat >> 7, col = flat & 127;
        float4 u = s4[(w + 16 * lrow) * 128 + col];
        float4 v = s4[(w + 16 * lrow + 256) * 128 + col];
        u.x += v.x; u.y += v.y; u.z += v.z; u.w += v.w;
        l4[lrow * 128 + col] = u;
      }
    }
    __syncthreads();
    const int g = t >> 7;            // 0..3
    const int x4 = (t & 127) * 4;
    float4 acc[4];
    pass1_core(L, t, 2 * g, acc);
    float* outB = B1 + (size_t)b * 256 * NN;
#pragma unroll
    for (int jj = 0; jj < 4; ++jj) {
      const int j = 4 * jj + g;
      *(float4*)&outB[(size_t)(j * 16 + w) * NN + x4] = acc[jj];
    }
  }
}

// ---- K2: blocks 0..31 = pass1 case-A (A0 -> A1);
//          blocks 32..47 = pass2 case-B (B1 -> out rows 512..767) ----------
__global__ __launch_bounds__(512) void k_p1a_p2b(const float* __restrict__ A0,
                                                 const float* __restrict__ B1,
                                                 float* __restrict__ A1,
                                                 float2* __restrict__ out) {
  __shared__ float L[16 * 512];
  const int bx = blockIdx.x, b = blockIdx.y;
  const int t = threadIdx.x;

  if (bx < 32) {
    const int c = bx >> 4;           // 0..1
    const int w = bx & 15;
    {
      const float4* s4 = (const float4*)(A0 + (size_t)b * 512 * NN);
      float4* l4 = (float4*)L;
      const int pbase = c * 256 + w;  // parent row bb: pbase + 16*bb
      for (int it = 0; it < 4; ++it) {
        int flat = it * 512 + t;  // 2048 float4
        int lrow = flat >> 7, col = flat & 127;
        l4[lrow * 128 + col] = s4[(pbase + 16 * lrow) * 128 + col];
      }
    }
    __syncthreads();
    const int g = t >> 7;            // 0..3
    const int x4 = (t & 127) * 4;
    float4 acc[4];
    pass1_core(L, t, c + 2 * g, acc);
    float* outA = A1 + (size_t)b * 512 * NN;
#pragma unroll
    for (int jj = 0; jj < 4; ++jj) {
      const int C = c + 2 * g + 8 * jj;
      *(float4*)&outA[(size_t)(C * 16 + w) * NN + x4] = acc[jj];
    }
  } else {
    const int a = bx - 32;           // 0..15
    const int c = 2 * a;
    const float* in = B1 + (size_t)b * 256 * NN + (size_t)a * 16 * NN;
    {
      const float4* s4 = (const float4*)in;
      float4* l4 = (float4*)L;
      for (int it = 0; it < 4; ++it) l4[it * 512 + t] = s4[it * 512 + t];
    }
    __syncthreads();
    pass2_core(L, t, c, 512 + a, 16, b, out);
  }
}

// ---- K3: pass 2 case-A (A1 -> out rows m = c + 32j) ----------------------
__global__ __launch_bounds__(512) void k_pass2A(const float* __restrict__ A1,
                                                float2* __restrict__ out) {
  __shared__ float L[16 * 512];
  const int c = blockIdx.x, b = blockIdx.y;
  const int t = threadIdx.x;  // = x
  const float* in = A1 + (size_t)b * 512 * NN + (size_t)c * 16 * NN;
  {
    const float4* s4 = (const float4*)in;
    float4* l4 = (float4*)L;
    for (int it = 0; it < 4; ++it) l4[it * 512 + t] = s4[it * 512 + t];
  }
  __syncthreads();
  pass2_core(L, t, c, c, 32, b, out);
}

// ================= fallback: round-1 direct shear-sum =====================
#define TM 16
#define YT 16
#define LDS_STRIDE 516
__global__ __launch_bounds__(512) void drt_main(const float* __restrict__ img,
                                                float* __restrict__ out) {
  __shared__ float rows[YT * LDS_STRIDE];
  const int b = blockIdx.y;
  const int tile = blockIdx.x;
  const int t = threadIdx.x;
  const bool caseB = (tile >= 32);
  const int a0 = caseB ? (tile - 32) * TM : tile * TM;
  const float* __restrict__ src = img + (size_t)b * (NN * NN);
  const int slope0 = caseB ? (2 * a0) : a0;
  const int dslope = caseB ? 2 : 1;
  float acc[TM];
#pragma unroll
  for (int i = 0; i < TM; ++i) acc[i] = 0.0f;
  for (int y0 = 0; y0 < NN; y0 += YT) {
    __syncthreads();
    if (caseB) {
#pragma unroll
      for (int r = 0; r < YT; ++r) rows[r * LDS_STRIDE + t] = src[(y0 + r) * NN + t];
    } else {
#pragma unroll
      for (int rep = 0; rep < YT; ++rep) {
        int idx = rep * NN + t;
        int xx = idx >> 4, cc = idx & 15;
        rows[cc * LDS_STRIDE + xx] = src[xx * NN + y0 + cc];
      }
    }
    __syncthreads();
#pragma unroll 4
    for (int r = 0; r < YT; ++r) {
      const int v = y0 + r;
      int base = t - slope0 * v;
      const int step = dslope * v;
      const float* __restrict__ rowp = rows + r * LDS_STRIDE;
#pragma unroll
      for (int i = 0; i < TM; ++i) { acc[i] += rowp[base & MASK]; base -= step; }
    }
  }
  const int m = caseB ? (NN + a0) : a0;
  float2* outp = (float2*)out;
#pragma unroll
  for (int i = 0; i < TM; ++i) {
    float2 vv; vv.x = acc[i] * SCALE; vv.y = 0.0f;
    outp[((size_t)b * MU + (m + i)) * NN + t] = vv;
  }
}

extern "C" void kernel_launch(void* const* d_in, const int* in_sizes, int n_in,
                              void* d_out, int out_size, void* d_ws, size_t ws_size,
                              hipStream_t stream) {
  const float* img = (const float*)d_in[0];
  if (ws_size < (size_t)42 * 1024 * 1024) {
    drt_main<<<dim3(48, 16), dim3(512), 0, stream>>>(img, (float*)d_out);
    return;
  }
  float* W  = (float*)d_ws;
  float* A0 = W;                 // 16 x 512 x 512
  float* A1 = W + 4194304;       // 16 x 512 x 512
  float* B1 = W + 8388608;       // 16 x 256 x 512
  float2* outp = (float2*)d_out;

  k_init_p1b<<<dim3(48, 16), dim3(512), 0, stream>>>(img, A0, B1);
  k_p1a_p2b <<<dim3(48, 16), dim3(512), 0, stream>>>(A0, B1, A1, outp);
  k_pass2A  <<<dim3(32, 16), dim3(512), 0, stream>>>(A1, outp);
}